// Round 6
// baseline (460.691 us; speedup 1.0000x reference)
//
#include <hip/hip_runtime.h>

// Problem constants (from the reference file)
#define N_NODES 50000
#define N_EDGES 800000
#define F_IN_D  128
#define H_DIM   256
#define L_DIM   64
#define G_NUM   500

typedef unsigned int   u32;
typedef unsigned short u16;
typedef __attribute__((ext_vector_type(8))) short short8;
typedef __attribute__((ext_vector_type(4))) float f32x4;

static __device__ __forceinline__ float bf2f(u16 u) {
    union { u32 i; float f; } x; x.i = ((u32)u) << 16; return x.f;
}
static __device__ __forceinline__ u16 f2bf(float f) {
    union { float f; u32 i; } x; x.f = f;
    u32 r = (x.i + 0x7fffu + ((x.i >> 16) & 1u)) >> 16;
    return (u16)r;
}

// B-swizzle address (in u16 units): fragment layout for mfma_16x16x32_bf16.
static __device__ __forceinline__ u32 bswz_idx(int n, int k, int plane, int KS) {
    int n0g = n >> 6, nt = (n >> 4) & 3, lr = n & 15;
    int k0i = k >> 5, ks = k & 31, lq = ks >> 3, j = ks & 7;
    return ((u32)((((n0g * KS + k0i) * 2 + plane) * 4 + nt) * 64 + lq * 16 + lr)) * 8 + j;
}

// ---------------------------------------------------------------------------
// Graph preprocessing
// ---------------------------------------------------------------------------
// degree histogram only — random-address atomics parallelize across channels.
__global__ void count_kernel(const int* __restrict__ dst, int* __restrict__ hist) {
    int i = blockIdx.x * 256 + threadIdx.x;
    if (i < N_EDGES) atomicAdd(&hist[dst[i]], 1);
}

// batch is sorted: graph start offsets via boundary detection, no atomics.
__global__ void bounds_kernel(const int* __restrict__ batch, int* __restrict__ goff) {
    int i = blockIdx.x * 256 + threadIdx.x;
    if (i >= N_NODES) return;
    int b = batch[i];
    if (i == 0) {
        for (int g = 0; g <= b; ++g) goff[g] = 0;
    } else {
        int p = batch[i - 1];
        for (int g = p + 1; g <= b; ++g) goff[g] = i;
    }
    if (i == N_NODES - 1) {
        for (int g = b + 1; g <= G_NUM; ++g) goff[g] = N_NODES;
    }
}

// exclusive scan of hist (chunk=256) + fused dinv computation
__global__ void scan_chunk_kernel(const int* __restrict__ in, int* __restrict__ excl,
                                  int* __restrict__ partials, float* __restrict__ dinv, int n) {
    __shared__ int sm[256];
    int t = threadIdx.x;
    int i = blockIdx.x * 256 + t;
    int v = (i < n) ? in[i] : 0;
    sm[t] = v; __syncthreads();
    for (int off = 1; off < 256; off <<= 1) {
        int x = (t >= off) ? sm[t - off] : 0;
        __syncthreads();
        sm[t] += x;
        __syncthreads();
    }
    if (i < n) {
        excl[i] = sm[t] - v;
        dinv[i] = 1.0f / sqrtf((float)(v + 1));   // +1 self loop
    }
    if (t == 255) partials[blockIdx.x] = sm[255];
}

__global__ void scan_part_kernel(int* __restrict__ partials, int nb, int* __restrict__ total_out) {
    __shared__ int sm[256];
    int t = threadIdx.x;
    int v = (t < nb) ? partials[t] : 0;
    sm[t] = v; __syncthreads();
    for (int off = 1; off < 256; off <<= 1) {
        int x = (t >= off) ? sm[t - off] : 0;
        __syncthreads();
        sm[t] += x;
        __syncthreads();
    }
    if (t < nb) partials[t] = sm[t] - v;
    if (t == 255) *total_out = sm[255];
}

__global__ void scan_final_kernel(const int* __restrict__ excl, const int* __restrict__ partials,
                                  int* __restrict__ out, int* __restrict__ cursor, int n) {
    int i = blockIdx.x * 256 + threadIdx.x;
    if (i < n) {
        int v = excl[i] + partials[blockIdx.x];
        out[i] = v;
        cursor[i] = v;
    }
}

// CSR entries packed (src, bits(dinv[src]))
__global__ void place_kernel(const int* __restrict__ src, const int* __restrict__ dst,
                             const float* __restrict__ dinv,
                             int* __restrict__ cursor, uint2* __restrict__ csr) {
    int e = blockIdx.x * 256 + threadIdx.x;
    if (e < N_EDGES) {
        int s = src[e];
        int d = dst[e];
        int pos = atomicAdd(&cursor[d], 1);
        csr[pos] = make_uint2((u32)s, __float_as_uint(dinv[s]));
    }
}

// ---------------------------------------------------------------------------
// All dtype conversions in one launch
// ---------------------------------------------------------------------------
#define NXQ (N_NODES * F_IN_D / 4)          // 1,600,000
#define NW1 (F_IN_D * H_DIM)                // 32,768
#define NW2 (H_DIM * H_DIM)                 // 65,536
__global__ void conv_kernel(const float* __restrict__ x, u16* __restrict__ xb,
                            const float* __restrict__ W1, u16* __restrict__ w1swz,
                            const float* __restrict__ W2, u16* __restrict__ w2swz) {
    int i = blockIdx.x * 256 + threadIdx.x;
    if (i < NXQ) {
        float4 v = *(const float4*)&x[(size_t)i * 4];
        ushort4 o;
        o.x = f2bf(v.x); o.y = f2bf(v.y); o.z = f2bf(v.z); o.w = f2bf(v.w);
        *(ushort4*)&xb[(size_t)i * 4] = o;
    } else if (i < NXQ + NW1) {
        int idx = i - NXQ;
        int k = idx >> 8, n = idx & 255;
        float w = W1[idx];
        u16 h = f2bf(w);
        w1swz[bswz_idx(n, k, 0, F_IN_D / 32)] = h;
        w1swz[bswz_idx(n, k, 1, F_IN_D / 32)] = f2bf(w - bf2f(h));
    } else if (i < NXQ + NW1 + NW2) {
        int idx = i - NXQ - NW1;
        int k = idx >> 8, n = idx & 255;
        float w = W2[idx];
        u16 h = f2bf(w);
        w2swz[bswz_idx(n, k, 0, H_DIM / 32)] = h;
        w2swz[bswz_idx(n, k, 1, H_DIM / 32)] = f2bf(w - bf2f(h));
    }
}

// ---------------------------------------------------------------------------
// Fused aggregate + MFMA GEMM (+ optional mean-pool).
//   stage 1: each wave aggregates 16 of the block's 64 nodes into LDS (bf16)
//   stage 2: GEMM 64x256xIN_D from the LDS A-tile, B pre-swizzled (1 KB segs)
//   epilogue: bias+relu -> bf16; either store rows (POOL=false) or
//             segment-sum into pooled[] (POOL=true; batch sorted).
// LDS A-tile (row stride 264) is reused as the epilogue staging tile.
// ---------------------------------------------------------------------------
template<int IN_D, bool POOL>
__global__ __launch_bounds__(256, 3)
void fused_kernel(const u16* __restrict__ In, const float* __restrict__ dinv,
                  const int* __restrict__ rp, const uint2* __restrict__ csr,
                  const short8* __restrict__ Bswz, const float* __restrict__ bias,
                  u16* __restrict__ Out, const int* __restrict__ batch,
                  float* __restrict__ pooled, int M) {
    const int KS = IN_D / 32;
    const int AP = IN_D + 8;           // padded A row (u16): 2-way bank alias = free
    __shared__ u16 buf[64 * 264];      // stage1/2: A-tile (stride AP); epilogue: out tile (stride 264)
    __shared__ int batch_s[64];
    int tid  = threadIdx.x;
    int wave = tid >> 6, lane = tid & 63;
    int m0 = blockIdx.x * 64;

    // ---------------- stage 1: aggregate 16 nodes per wave into LDS --------
    for (int i = 0; i < 16; ++i) {
        int ln = wave * 16 + i;
        int node = m0 + ln;
        if (IN_D == 128) {
            int c = lane * 2;
            u32 o = 0;
            if (node < M) {
                float di = dinv[node];
                int r0 = rp[node], r1 = rp[node + 1];
                u32 sv = *(const u32*)&In[(size_t)node * 128 + c];
                float a0 = di * bf2f((u16)(sv & 0xffff));
                float a1 = di * bf2f((u16)(sv >> 16));
                int j = r0;
                for (; j + 4 <= r1; j += 4) {
                    uint2 e0 = csr[j], e1 = csr[j + 1], e2 = csr[j + 2], e3 = csr[j + 3];
                    u32 v0 = *(const u32*)&In[(size_t)e0.x * 128 + c];
                    u32 v1 = *(const u32*)&In[(size_t)e1.x * 128 + c];
                    u32 v2 = *(const u32*)&In[(size_t)e2.x * 128 + c];
                    u32 v3 = *(const u32*)&In[(size_t)e3.x * 128 + c];
                    float w0 = __uint_as_float(e0.y), w1 = __uint_as_float(e1.y);
                    float w2 = __uint_as_float(e2.y), w3 = __uint_as_float(e3.y);
                    a0 = fmaf(w0, bf2f((u16)(v0 & 0xffff)), a0);
                    a1 = fmaf(w0, bf2f((u16)(v0 >> 16)), a1);
                    a0 = fmaf(w1, bf2f((u16)(v1 & 0xffff)), a0);
                    a1 = fmaf(w1, bf2f((u16)(v1 >> 16)), a1);
                    a0 = fmaf(w2, bf2f((u16)(v2 & 0xffff)), a0);
                    a1 = fmaf(w2, bf2f((u16)(v2 >> 16)), a1);
                    a0 = fmaf(w3, bf2f((u16)(v3 & 0xffff)), a0);
                    a1 = fmaf(w3, bf2f((u16)(v3 >> 16)), a1);
                }
                for (; j < r1; ++j) {
                    uint2 e = csr[j];
                    u32 v = *(const u32*)&In[(size_t)e.x * 128 + c];
                    float w = __uint_as_float(e.y);
                    a0 = fmaf(w, bf2f((u16)(v & 0xffff)), a0);
                    a1 = fmaf(w, bf2f((u16)(v >> 16)), a1);
                }
                o = ((u32)f2bf(di * a1) << 16) | (u32)f2bf(di * a0);
            }
            *(u32*)&buf[ln * AP + c] = o;
        } else {
            int c = lane * 4;
            uint2 o = make_uint2(0, 0);
            if (node < M) {
                float di = dinv[node];
                int r0 = rp[node], r1 = rp[node + 1];
                uint2 sv = *(const uint2*)&In[(size_t)node * 256 + c];
                float a0 = di * bf2f((u16)(sv.x & 0xffff));
                float a1 = di * bf2f((u16)(sv.x >> 16));
                float a2 = di * bf2f((u16)(sv.y & 0xffff));
                float a3 = di * bf2f((u16)(sv.y >> 16));
                int j = r0;
                for (; j + 4 <= r1; j += 4) {
                    uint2 e0 = csr[j], e1 = csr[j + 1], e2 = csr[j + 2], e3 = csr[j + 3];
                    uint2 v0 = *(const uint2*)&In[(size_t)e0.x * 256 + c];
                    uint2 v1 = *(const uint2*)&In[(size_t)e1.x * 256 + c];
                    uint2 v2 = *(const uint2*)&In[(size_t)e2.x * 256 + c];
                    uint2 v3 = *(const uint2*)&In[(size_t)e3.x * 256 + c];
                    float w0 = __uint_as_float(e0.y), w1 = __uint_as_float(e1.y);
                    float w2 = __uint_as_float(e2.y), w3 = __uint_as_float(e3.y);
                    a0 = fmaf(w0, bf2f((u16)(v0.x & 0xffff)), a0);
                    a1 = fmaf(w0, bf2f((u16)(v0.x >> 16)), a1);
                    a2 = fmaf(w0, bf2f((u16)(v0.y & 0xffff)), a2);
                    a3 = fmaf(w0, bf2f((u16)(v0.y >> 16)), a3);
                    a0 = fmaf(w1, bf2f((u16)(v1.x & 0xffff)), a0);
                    a1 = fmaf(w1, bf2f((u16)(v1.x >> 16)), a1);
                    a2 = fmaf(w1, bf2f((u16)(v1.y & 0xffff)), a2);
                    a3 = fmaf(w1, bf2f((u16)(v1.y >> 16)), a3);
                    a0 = fmaf(w2, bf2f((u16)(v2.x & 0xffff)), a0);
                    a1 = fmaf(w2, bf2f((u16)(v2.x >> 16)), a1);
                    a2 = fmaf(w2, bf2f((u16)(v2.y & 0xffff)), a2);
                    a3 = fmaf(w2, bf2f((u16)(v2.y >> 16)), a3);
                    a0 = fmaf(w3, bf2f((u16)(v3.x & 0xffff)), a0);
                    a1 = fmaf(w3, bf2f((u16)(v3.x >> 16)), a1);
                    a2 = fmaf(w3, bf2f((u16)(v3.y & 0xffff)), a2);
                    a3 = fmaf(w3, bf2f((u16)(v3.y >> 16)), a3);
                }
                for (; j < r1; ++j) {
                    uint2 e = csr[j];
                    uint2 v = *(const uint2*)&In[(size_t)e.x * 256 + c];
                    float w = __uint_as_float(e.y);
                    a0 = fmaf(w, bf2f((u16)(v.x & 0xffff)), a0);
                    a1 = fmaf(w, bf2f((u16)(v.x >> 16)), a1);
                    a2 = fmaf(w, bf2f((u16)(v.y & 0xffff)), a2);
                    a3 = fmaf(w, bf2f((u16)(v.y >> 16)), a3);
                }
                o.x = ((u32)f2bf(di * a1) << 16) | (u32)f2bf(di * a0);
                o.y = ((u32)f2bf(di * a3) << 16) | (u32)f2bf(di * a2);
            }
            *(uint2*)&buf[ln * AP + c] = o;
        }
    }
    __syncthreads();

    // ---------------- stage 2: GEMM from LDS A-tile -------------------------
    int n0 = wave * 64;
    int lr = lane & 15;
    int lk = (lane >> 4) * 8;

    f32x4 acc[4][4];
#pragma unroll
    for (int i = 0; i < 4; ++i)
#pragma unroll
        for (int j = 0; j < 4; ++j) acc[i][j] = {0.f, 0.f, 0.f, 0.f};

    for (int k0i = 0; k0i < KS; ++k0i) {
        short8 a[4], bh[4], bl[4];
#pragma unroll
        for (int mt = 0; mt < 4; ++mt)
            a[mt] = *(const short8*)&buf[(mt * 16 + lr) * AP + k0i * 32 + lk];
        const short8* bp = Bswz + ((size_t)(wave * KS + k0i) * 8) * 64 + lane;
#pragma unroll
        for (int nt = 0; nt < 4; ++nt) {
            bh[nt] = bp[(size_t)nt * 64];
            bl[nt] = bp[(size_t)(4 + nt) * 64];
        }
#pragma unroll
        for (int mt = 0; mt < 4; ++mt)
#pragma unroll
            for (int nt = 0; nt < 4; ++nt) {
                acc[mt][nt] = __builtin_amdgcn_mfma_f32_16x16x32_bf16(a[mt], bh[nt], acc[mt][nt], 0, 0, 0);
                acc[mt][nt] = __builtin_amdgcn_mfma_f32_16x16x32_bf16(a[mt], bl[nt], acc[mt][nt], 0, 0, 0);
            }
    }

    if (POOL && tid < 64) {
        int m = m0 + tid;
        batch_s[tid] = (m < M) ? batch[m] : -1;
    }
    __syncthreads();   // A-tile dead; reuse buf as epilogue tile (stride 264)

#pragma unroll
    for (int mt = 0; mt < 4; ++mt)
#pragma unroll
        for (int nt = 0; nt < 4; ++nt) {
            int col = n0 + nt * 16 + lr;
            float b = bias[col];
#pragma unroll
            for (int r = 0; r < 4; ++r) {
                int row = mt * 16 + (lane >> 4) * 4 + r;
                buf[row * 264 + col] = f2bf(fmaxf(acc[mt][nt][r] + b, 0.f));
            }
        }
    __syncthreads();

    if (POOL) {
        // segmented pooling: thread = column, walk the block's sorted rows
        int rows = M - m0; if (rows > 64) rows = 64;
        float s = 0.f;
        int gp = batch_s[0];
        for (int r = 0; r < rows; ++r) {
            int g = batch_s[r];
            if (g != gp) {
                atomicAdd(&pooled[(size_t)gp * H_DIM + tid], s);
                s = 0.f;
                gp = g;
            }
            s += bf2f(buf[r * 264 + tid]);
        }
        atomicAdd(&pooled[(size_t)gp * H_DIM + tid], s);
    } else {
#pragma unroll
        for (int p = 0; p < 8; ++p) {
            int row = p * 8 + (tid >> 5);
            int c16 = (tid & 31) * 8;
            int m = m0 + row;
            if (m < M) {
                uint4 v = *(const uint4*)&buf[row * 264 + c16];
                *(uint4*)&Out[(size_t)m * 256 + c16] = v;
            }
        }
    }
}

// ---------------------------------------------------------------------------
// Heads (fp32): h_graph = pooled/cnt (cnt from goff diffs); mu/logvar heads
// ---------------------------------------------------------------------------
__global__ void head_kernel(const float* __restrict__ pooled, const int* __restrict__ goff,
                            const float* __restrict__ Wmu, const float* __restrict__ bmu,
                            const float* __restrict__ Wlv, const float* __restrict__ blv,
                            float* __restrict__ out) {
    __shared__ float hg[H_DIM];
    int g = blockIdx.x, l = threadIdx.x;   // 64 threads
    float inv = 1.0f / fmaxf((float)(goff[g + 1] - goff[g]), 1.0f);
    for (int k = l; k < H_DIM; k += 64) hg[k] = pooled[(size_t)g * H_DIM + k] * inv;
    __syncthreads();
    float mu = bmu[l], lv = blv[l];
    for (int k = 0; k < H_DIM; ++k) {
        float h = hg[k];
        mu = fmaf(h, Wmu[k * L_DIM + l], mu);
        lv = fmaf(h, Wlv[k * L_DIM + l], lv);
    }
    out[(size_t)g * L_DIM + l] = mu;
    out[(size_t)G_NUM * L_DIM + (size_t)g * L_DIM + l] = lv;
}

// ---------------------------------------------------------------------------
extern "C" void kernel_launch(void* const* d_in, const int* in_sizes, int n_in,
                              void* d_out, int out_size, void* d_ws, size_t ws_size,
                              hipStream_t stream) {
    const float* x     = (const float*)d_in[0];
    const int*   ei    = (const int*)  d_in[1];
    const int*   batch = (const int*)  d_in[2];
    const float* W1  = (const float*)d_in[4];
    const float* b1  = (const float*)d_in[5];
    const float* W2  = (const float*)d_in[6];
    const float* b2  = (const float*)d_in[7];
    const float* Wmu = (const float*)d_in[8];
    const float* bmu = (const float*)d_in[9];
    const float* Wlv = (const float*)d_in[10];
    const float* blv = (const float*)d_in[11];
    const int* src = ei;
    const int* dst = ei + N_EDGES;

    char* ws = (char*)d_ws;
    size_t off = 0;
    auto alloc = [&](size_t bytes) -> void* {
        void* p = ws + off;
        off += (bytes + 255) & ~(size_t)255;
        return p;
    };
    int*   hist     = (int*)alloc((size_t)N_NODES * 4);
    float* dinv     = (float*)alloc((size_t)N_NODES * 4);
    int*   row_ptr  = (int*)alloc((size_t)(N_NODES + 1) * 4);
    int*   cursor   = (int*)alloc((size_t)N_NODES * 4);
    uint2* csr      = (uint2*)alloc((size_t)N_EDGES * 8);
    int*   excl     = (int*)alloc((size_t)N_NODES * 4);
    int*   partials = (int*)alloc(256 * 4);
    int*   goff     = (int*)alloc((size_t)(G_NUM + 1) * 4);
    u16*   xb    = (u16*)alloc((size_t)N_NODES * F_IN_D * 2);  // 12.8 MB
    u16*   H1    = (u16*)alloc((size_t)N_NODES * H_DIM * 2);   // 25.6 MB
    u16*   w1swz = (u16*)alloc((size_t)2 * F_IN_D * H_DIM * 2);
    u16*   w2swz = (u16*)alloc((size_t)2 * H_DIM * H_DIM * 2);
    float* pooled = (float*)alloc((size_t)G_NUM * H_DIM * 4);
    (void)ws_size; (void)n_in; (void)in_sizes; (void)out_size;

    const int NB_SCAN = (N_NODES + 255) / 256;   // 196
    const int GEMM_NB = (N_NODES + 63) / 64;     // 782

    hipMemsetAsync(hist, 0, (size_t)N_NODES * 4, stream);
    hipMemsetAsync(pooled, 0, (size_t)G_NUM * H_DIM * 4, stream);
    count_kernel<<<(N_EDGES + 255) / 256, 256, 0, stream>>>(dst, hist);
    bounds_kernel<<<NB_SCAN, 256, 0, stream>>>(batch, goff);
    scan_chunk_kernel<<<NB_SCAN, 256, 0, stream>>>(hist, excl, partials, dinv, N_NODES);
    scan_part_kernel <<<1, 256, 0, stream>>>(partials, NB_SCAN, row_ptr + N_NODES);
    scan_final_kernel<<<NB_SCAN, 256, 0, stream>>>(excl, partials, row_ptr, cursor, N_NODES);
    place_kernel<<<(N_EDGES + 255) / 256, 256, 0, stream>>>(src, dst, dinv, cursor, csr);
    conv_kernel <<<(NXQ + NW1 + NW2 + 255) / 256, 256, 0, stream>>>(x, xb, W1, w1swz, W2, w2swz);

    // layer 1: fused aggregate(x) + GEMM -> H1
    fused_kernel<F_IN_D, false><<<GEMM_NB, 256, 0, stream>>>(
        xb, dinv, row_ptr, csr, (const short8*)w1swz, b1, H1, nullptr, nullptr, N_NODES);
    // layer 2: fused aggregate(H1) + GEMM + mean-pool
    fused_kernel<H_DIM, true><<<GEMM_NB, 256, 0, stream>>>(
        H1, dinv, row_ptr, csr, (const short8*)w2swz, b2, nullptr, batch, pooled, N_NODES);

    head_kernel<<<G_NUM, 64, 0, stream>>>(pooled, goff, Wmu, bmu, Wlv, blv, (float*)d_out);
}

// Round 7
// 344.132 us; speedup vs baseline: 1.3387x; 1.3387x over previous
//
#include <hip/hip_runtime.h>

// Problem constants (from the reference file)
#define N_NODES 50000
#define N_EDGES 800000
#define F_IN_D  128
#define H_DIM   256
#define L_DIM   64
#define G_NUM   500

typedef unsigned int   u32;
typedef unsigned short u16;
typedef __attribute__((ext_vector_type(8))) short short8;
typedef __attribute__((ext_vector_type(4))) float f32x4;

static __device__ __forceinline__ float bf2f(u16 u) {
    union { u32 i; float f; } x; x.i = ((u32)u) << 16; return x.f;
}
static __device__ __forceinline__ u16 f2bf(float f) {
    union { float f; u32 i; } x; x.f = f;
    u32 r = (x.i + 0x7fffu + ((x.i >> 16) & 1u)) >> 16;
    return (u16)r;
}

// B-swizzle address (in u16 units): fragment layout for mfma_16x16x32_bf16.
static __device__ __forceinline__ u32 bswz_idx(int n, int k, int plane, int KS) {
    int n0g = n >> 6, nt = (n >> 4) & 3, lr = n & 15;
    int k0i = k >> 5, ks = k & 31, lq = ks >> 3, j = ks & 7;
    return ((u32)((((n0g * KS + k0i) * 2 + plane) * 4 + nt) * 64 + lq * 16 + lr)) * 8 + j;
}

// ---------------------------------------------------------------------------
// Graph preprocessing
// ---------------------------------------------------------------------------
// degree histogram only — random-address atomics parallelize across channels.
__global__ void count_kernel(const int* __restrict__ dst, int* __restrict__ hist) {
    int i = blockIdx.x * 256 + threadIdx.x;
    if (i < N_EDGES) atomicAdd(&hist[dst[i]], 1);
}

// batch is sorted: graph start offsets via boundary detection, no atomics.
__global__ void bounds_kernel(const int* __restrict__ batch, int* __restrict__ goff) {
    int i = blockIdx.x * 256 + threadIdx.x;
    if (i >= N_NODES) return;
    int b = batch[i];
    if (i == 0) {
        for (int g = 0; g <= b; ++g) goff[g] = 0;
    } else {
        int p = batch[i - 1];
        for (int g = p + 1; g <= b; ++g) goff[g] = i;
    }
    if (i == N_NODES - 1) {
        for (int g = b + 1; g <= G_NUM; ++g) goff[g] = N_NODES;
    }
}

// exclusive scan of hist (chunk=256) + fused dinv computation
__global__ void scan_chunk_kernel(const int* __restrict__ in, int* __restrict__ excl,
                                  int* __restrict__ partials, float* __restrict__ dinv, int n) {
    __shared__ int sm[256];
    int t = threadIdx.x;
    int i = blockIdx.x * 256 + t;
    int v = (i < n) ? in[i] : 0;
    sm[t] = v; __syncthreads();
    for (int off = 1; off < 256; off <<= 1) {
        int x = (t >= off) ? sm[t - off] : 0;
        __syncthreads();
        sm[t] += x;
        __syncthreads();
    }
    if (i < n) {
        excl[i] = sm[t] - v;
        dinv[i] = 1.0f / sqrtf((float)(v + 1));   // +1 self loop
    }
    if (t == 255) partials[blockIdx.x] = sm[255];
}

__global__ void scan_part_kernel(int* __restrict__ partials, int nb, int* __restrict__ total_out) {
    __shared__ int sm[256];
    int t = threadIdx.x;
    int v = (t < nb) ? partials[t] : 0;
    sm[t] = v; __syncthreads();
    for (int off = 1; off < 256; off <<= 1) {
        int x = (t >= off) ? sm[t - off] : 0;
        __syncthreads();
        sm[t] += x;
        __syncthreads();
    }
    if (t < nb) partials[t] = sm[t] - v;
    if (t == 255) *total_out = sm[255];
}

__global__ void scan_final_kernel(const int* __restrict__ excl, const int* __restrict__ partials,
                                  int* __restrict__ out, int* __restrict__ cursor, int n) {
    int i = blockIdx.x * 256 + threadIdx.x;
    if (i < n) {
        int v = excl[i] + partials[blockIdx.x];
        out[i] = v;
        cursor[i] = v;
    }
}

// CSR entries packed (src, bits(dinv[src]))
__global__ void place_kernel(const int* __restrict__ src, const int* __restrict__ dst,
                             const float* __restrict__ dinv,
                             int* __restrict__ cursor, uint2* __restrict__ csr) {
    int e = blockIdx.x * 256 + threadIdx.x;
    if (e < N_EDGES) {
        int s = src[e];
        int d = dst[e];
        int pos = atomicAdd(&cursor[d], 1);
        csr[pos] = make_uint2((u32)s, __float_as_uint(dinv[s]));
    }
}

// ---------------------------------------------------------------------------
// All dtype conversions in one launch
// ---------------------------------------------------------------------------
#define NXQ (N_NODES * F_IN_D / 4)          // 1,600,000
#define NW1 (F_IN_D * H_DIM)                // 32,768
#define NW2 (H_DIM * H_DIM)                 // 65,536
__global__ void conv_kernel(const float* __restrict__ x, u16* __restrict__ xb,
                            const float* __restrict__ W1, u16* __restrict__ w1swz,
                            const float* __restrict__ W2, u16* __restrict__ w2swz) {
    int i = blockIdx.x * 256 + threadIdx.x;
    if (i < NXQ) {
        float4 v = *(const float4*)&x[(size_t)i * 4];
        ushort4 o;
        o.x = f2bf(v.x); o.y = f2bf(v.y); o.z = f2bf(v.z); o.w = f2bf(v.w);
        *(ushort4*)&xb[(size_t)i * 4] = o;
    } else if (i < NXQ + NW1) {
        int idx = i - NXQ;
        int k = idx >> 8, n = idx & 255;
        float w = W1[idx];
        u16 h = f2bf(w);
        w1swz[bswz_idx(n, k, 0, F_IN_D / 32)] = h;
        w1swz[bswz_idx(n, k, 1, F_IN_D / 32)] = f2bf(w - bf2f(h));
    } else if (i < NXQ + NW1 + NW2) {
        int idx = i - NXQ - NW1;
        int k = idx >> 8, n = idx & 255;
        float w = W2[idx];
        u16 h = f2bf(w);
        w2swz[bswz_idx(n, k, 0, H_DIM / 32)] = h;
        w2swz[bswz_idx(n, k, 1, H_DIM / 32)] = f2bf(w - bf2f(h));
    }
}

// ---------------------------------------------------------------------------
// GCN aggregation, bf16 in -> bf16 out. One wave per node.
// Edge loop unrolled x8: 8 independent gathers in flight per wave
// (round-5 x4 was still latency-bound: HBM 45%, VALU 28%, MFMA 0).
// ---------------------------------------------------------------------------
__global__ __launch_bounds__(256)
void agg128_kernel(const u16* __restrict__ In, const float* __restrict__ dinv,
                   const int* __restrict__ rp, const uint2* __restrict__ csr,
                   u16* __restrict__ Out) {
    int node = blockIdx.x * 4 + (threadIdx.x >> 6);
    int lane = threadIdx.x & 63;
    if (node >= N_NODES) return;
    int c = lane * 2;
    float di = dinv[node];
    int r0 = rp[node], r1 = rp[node + 1];
    u32 sv = *(const u32*)&In[(size_t)node * 128 + c];
    float a0 = di * bf2f((u16)(sv & 0xffff));
    float a1 = di * bf2f((u16)(sv >> 16));
    int j = r0;
    for (; j + 8 <= r1; j += 8) {
        uint2 e[8];
        u32 v[8];
#pragma unroll
        for (int q = 0; q < 8; ++q) e[q] = csr[j + q];
#pragma unroll
        for (int q = 0; q < 8; ++q) v[q] = *(const u32*)&In[(size_t)e[q].x * 128 + c];
#pragma unroll
        for (int q = 0; q < 8; ++q) {
            float w = __uint_as_float(e[q].y);
            a0 = fmaf(w, bf2f((u16)(v[q] & 0xffff)), a0);
            a1 = fmaf(w, bf2f((u16)(v[q] >> 16)), a1);
        }
    }
    for (; j + 4 <= r1; j += 4) {
        uint2 e[4];
        u32 v[4];
#pragma unroll
        for (int q = 0; q < 4; ++q) e[q] = csr[j + q];
#pragma unroll
        for (int q = 0; q < 4; ++q) v[q] = *(const u32*)&In[(size_t)e[q].x * 128 + c];
#pragma unroll
        for (int q = 0; q < 4; ++q) {
            float w = __uint_as_float(e[q].y);
            a0 = fmaf(w, bf2f((u16)(v[q] & 0xffff)), a0);
            a1 = fmaf(w, bf2f((u16)(v[q] >> 16)), a1);
        }
    }
    for (; j < r1; ++j) {
        uint2 e = csr[j];
        u32 v = *(const u32*)&In[(size_t)e.x * 128 + c];
        float w = __uint_as_float(e.y);
        a0 = fmaf(w, bf2f((u16)(v & 0xffff)), a0);
        a1 = fmaf(w, bf2f((u16)(v >> 16)), a1);
    }
    u32 o = ((u32)f2bf(di * a1) << 16) | (u32)f2bf(di * a0);
    *(u32*)&Out[(size_t)node * 128 + c] = o;
}

__global__ __launch_bounds__(256)
void agg256_kernel(const u16* __restrict__ In, const float* __restrict__ dinv,
                   const int* __restrict__ rp, const uint2* __restrict__ csr,
                   u16* __restrict__ Out) {
    int node = blockIdx.x * 4 + (threadIdx.x >> 6);
    int lane = threadIdx.x & 63;
    if (node >= N_NODES) return;
    int c = lane * 4;
    float di = dinv[node];
    int r0 = rp[node], r1 = rp[node + 1];
    uint2 sv = *(const uint2*)&In[(size_t)node * 256 + c];
    float a0 = di * bf2f((u16)(sv.x & 0xffff));
    float a1 = di * bf2f((u16)(sv.x >> 16));
    float a2 = di * bf2f((u16)(sv.y & 0xffff));
    float a3 = di * bf2f((u16)(sv.y >> 16));
    int j = r0;
    for (; j + 8 <= r1; j += 8) {
        uint2 e[8];
        uint2 v[8];
#pragma unroll
        for (int q = 0; q < 8; ++q) e[q] = csr[j + q];
#pragma unroll
        for (int q = 0; q < 8; ++q) v[q] = *(const uint2*)&In[(size_t)e[q].x * 256 + c];
#pragma unroll
        for (int q = 0; q < 8; ++q) {
            float w = __uint_as_float(e[q].y);
            a0 = fmaf(w, bf2f((u16)(v[q].x & 0xffff)), a0);
            a1 = fmaf(w, bf2f((u16)(v[q].x >> 16)), a1);
            a2 = fmaf(w, bf2f((u16)(v[q].y & 0xffff)), a2);
            a3 = fmaf(w, bf2f((u16)(v[q].y >> 16)), a3);
        }
    }
    for (; j + 4 <= r1; j += 4) {
        uint2 e[4];
        uint2 v[4];
#pragma unroll
        for (int q = 0; q < 4; ++q) e[q] = csr[j + q];
#pragma unroll
        for (int q = 0; q < 4; ++q) v[q] = *(const uint2*)&In[(size_t)e[q].x * 256 + c];
#pragma unroll
        for (int q = 0; q < 4; ++q) {
            float w = __uint_as_float(e[q].y);
            a0 = fmaf(w, bf2f((u16)(v[q].x & 0xffff)), a0);
            a1 = fmaf(w, bf2f((u16)(v[q].x >> 16)), a1);
            a2 = fmaf(w, bf2f((u16)(v[q].y & 0xffff)), a2);
            a3 = fmaf(w, bf2f((u16)(v[q].y >> 16)), a3);
        }
    }
    for (; j < r1; ++j) {
        uint2 e = csr[j];
        uint2 v = *(const uint2*)&In[(size_t)e.x * 256 + c];
        float w = __uint_as_float(e.y);
        a0 = fmaf(w, bf2f((u16)(v.x & 0xffff)), a0);
        a1 = fmaf(w, bf2f((u16)(v.x >> 16)), a1);
        a2 = fmaf(w, bf2f((u16)(v.y & 0xffff)), a2);
        a3 = fmaf(w, bf2f((u16)(v.y >> 16)), a3);
    }
    uint2 o;
    o.x = ((u32)f2bf(di * a1) << 16) | (u32)f2bf(di * a0);
    o.y = ((u32)f2bf(di * a3) << 16) | (u32)f2bf(di * a2);
    *(uint2*)&Out[(size_t)node * 256 + c] = o;
}

// ---------------------------------------------------------------------------
// MFMA GEMM layer 1: H1[M,256] = relu( A[M,128] @ W1 + b1 ), bf16 out.
// ---------------------------------------------------------------------------
template<int K>
__global__ __launch_bounds__(256, 3)
void gemm1_kernel(const u16* __restrict__ A, const short8* __restrict__ Bswz,
                  const float* __restrict__ bias, u16* __restrict__ Out, int M) {
    const int KS = K / 32;
    __shared__ u16 cst[64][264];
    int tid  = threadIdx.x;
    int wave = tid >> 6, lane = tid & 63;
    int m0 = blockIdx.x * 64;
    int n0 = wave * 64;
    int lr = lane & 15;
    int lk = (lane >> 4) * 8;

    f32x4 acc[4][4];
#pragma unroll
    for (int i = 0; i < 4; ++i)
#pragma unroll
        for (int j = 0; j < 4; ++j) acc[i][j] = {0.f, 0.f, 0.f, 0.f};

    for (int k0i = 0; k0i < KS; ++k0i) {
        int k0 = k0i * 32;
        short8 a[4], bh[4], bl[4];
#pragma unroll
        for (int mt = 0; mt < 4; ++mt) {
            int m = m0 + mt * 16 + lr;
            if (m > M - 1) m = M - 1;
            a[mt] = *(const short8*)&A[(size_t)m * K + k0 + lk];
        }
        const short8* bp = Bswz + ((size_t)(wave * KS + k0i) * 8) * 64 + lane;
#pragma unroll
        for (int nt = 0; nt < 4; ++nt) {
            bh[nt] = bp[(size_t)nt * 64];
            bl[nt] = bp[(size_t)(4 + nt) * 64];
        }
#pragma unroll
        for (int mt = 0; mt < 4; ++mt)
#pragma unroll
            for (int nt = 0; nt < 4; ++nt) {
                acc[mt][nt] = __builtin_amdgcn_mfma_f32_16x16x32_bf16(a[mt], bh[nt], acc[mt][nt], 0, 0, 0);
                acc[mt][nt] = __builtin_amdgcn_mfma_f32_16x16x32_bf16(a[mt], bl[nt], acc[mt][nt], 0, 0, 0);
            }
    }

#pragma unroll
    for (int mt = 0; mt < 4; ++mt)
#pragma unroll
        for (int nt = 0; nt < 4; ++nt) {
            int col = n0 + nt * 16 + lr;
            float b = bias[col];
#pragma unroll
            for (int r = 0; r < 4; ++r) {
                int row = mt * 16 + (lane >> 4) * 4 + r;
                cst[row][col] = f2bf(fmaxf(acc[mt][nt][r] + b, 0.f));
            }
        }
    __syncthreads();
#pragma unroll
    for (int p = 0; p < 8; ++p) {
        int row = p * 8 + (tid >> 5);
        int c16 = (tid & 31) * 8;
        int m = m0 + row;
        if (m < M) {
            uint4 v = *(const uint4*)&cst[row][c16];
            *(uint4*)&Out[(size_t)m * 256 + c16] = v;
        }
    }
}

// ---------------------------------------------------------------------------
// MFMA GEMM layer 2 + fused mean-pool
// ---------------------------------------------------------------------------
__global__ __launch_bounds__(256, 3)
void gemm2_pool_kernel(const u16* __restrict__ A, const short8* __restrict__ Bswz,
                       const float* __restrict__ bias, const int* __restrict__ batch,
                       float* __restrict__ pooled, int M) {
    const int K = H_DIM, KS = K / 32;
    __shared__ u16 cst[64][264];
    __shared__ int batch_s[64];
    int tid  = threadIdx.x;
    int wave = tid >> 6, lane = tid & 63;
    int m0 = blockIdx.x * 64;
    int n0 = wave * 64;
    int lr = lane & 15;
    int lk = (lane >> 4) * 8;

    f32x4 acc[4][4];
#pragma unroll
    for (int i = 0; i < 4; ++i)
#pragma unroll
        for (int j = 0; j < 4; ++j) acc[i][j] = {0.f, 0.f, 0.f, 0.f};

    for (int k0i = 0; k0i < KS; ++k0i) {
        int k0 = k0i * 32;
        short8 a[4], bh[4], bl[4];
#pragma unroll
        for (int mt = 0; mt < 4; ++mt) {
            int m = m0 + mt * 16 + lr;
            if (m > M - 1) m = M - 1;
            a[mt] = *(const short8*)&A[(size_t)m * K + k0 + lk];
        }
        const short8* bp = Bswz + ((size_t)(wave * KS + k0i) * 8) * 64 + lane;
#pragma unroll
        for (int nt = 0; nt < 4; ++nt) {
            bh[nt] = bp[(size_t)nt * 64];
            bl[nt] = bp[(size_t)(4 + nt) * 64];
        }
#pragma unroll
        for (int mt = 0; mt < 4; ++mt)
#pragma unroll
            for (int nt = 0; nt < 4; ++nt) {
                acc[mt][nt] = __builtin_amdgcn_mfma_f32_16x16x32_bf16(a[mt], bh[nt], acc[mt][nt], 0, 0, 0);
                acc[mt][nt] = __builtin_amdgcn_mfma_f32_16x16x32_bf16(a[mt], bl[nt], acc[mt][nt], 0, 0, 0);
            }
    }

    if (tid < 64) {
        int m = m0 + tid;
        batch_s[tid] = (m < M) ? batch[m] : -1;
    }
#pragma unroll
    for (int mt = 0; mt < 4; ++mt)
#pragma unroll
        for (int nt = 0; nt < 4; ++nt) {
            int col = n0 + nt * 16 + lr;
            float b = bias[col];
#pragma unroll
            for (int r = 0; r < 4; ++r) {
                int row = mt * 16 + (lane >> 4) * 4 + r;
                cst[row][col] = f2bf(fmaxf(acc[mt][nt][r] + b, 0.f));
            }
        }
    __syncthreads();

    // segmented pooling: thread = column, walk the 64 sorted rows
    int rows = M - m0; if (rows > 64) rows = 64;
    float s = 0.f;
    int gp = batch_s[0];
    for (int r = 0; r < rows; ++r) {
        int g = batch_s[r];
        if (g != gp) {
            atomicAdd(&pooled[(size_t)gp * H_DIM + tid], s);
            s = 0.f;
            gp = g;
        }
        s += bf2f(cst[r][tid]);
    }
    atomicAdd(&pooled[(size_t)gp * H_DIM + tid], s);
}

// ---------------------------------------------------------------------------
// Heads (fp32): h_graph = pooled/cnt (cnt from goff diffs); mu/logvar heads
// ---------------------------------------------------------------------------
__global__ void head_kernel(const float* __restrict__ pooled, const int* __restrict__ goff,
                            const float* __restrict__ Wmu, const float* __restrict__ bmu,
                            const float* __restrict__ Wlv, const float* __restrict__ blv,
                            float* __restrict__ out) {
    __shared__ float hg[H_DIM];
    int g = blockIdx.x, l = threadIdx.x;   // 64 threads
    float inv = 1.0f / fmaxf((float)(goff[g + 1] - goff[g]), 1.0f);
    for (int k = l; k < H_DIM; k += 64) hg[k] = pooled[(size_t)g * H_DIM + k] * inv;
    __syncthreads();
    float mu = bmu[l], lv = blv[l];
    for (int k = 0; k < H_DIM; ++k) {
        float h = hg[k];
        mu = fmaf(h, Wmu[k * L_DIM + l], mu);
        lv = fmaf(h, Wlv[k * L_DIM + l], lv);
    }
    out[(size_t)g * L_DIM + l] = mu;
    out[(size_t)G_NUM * L_DIM + (size_t)g * L_DIM + l] = lv;
}

// ---------------------------------------------------------------------------
extern "C" void kernel_launch(void* const* d_in, const int* in_sizes, int n_in,
                              void* d_out, int out_size, void* d_ws, size_t ws_size,
                              hipStream_t stream) {
    const float* x     = (const float*)d_in[0];
    const int*   ei    = (const int*)  d_in[1];
    const int*   batch = (const int*)  d_in[2];
    const float* W1  = (const float*)d_in[4];
    const float* b1  = (const float*)d_in[5];
    const float* W2  = (const float*)d_in[6];
    const float* b2  = (const float*)d_in[7];
    const float* Wmu = (const float*)d_in[8];
    const float* bmu = (const float*)d_in[9];
    const float* Wlv = (const float*)d_in[10];
    const float* blv = (const float*)d_in[11];
    const int* src = ei;
    const int* dst = ei + N_EDGES;

    char* ws = (char*)d_ws;
    size_t off = 0;
    auto alloc = [&](size_t bytes) -> void* {
        void* p = ws + off;
        off += (bytes + 255) & ~(size_t)255;
        return p;
    };
    int*   hist     = (int*)alloc((size_t)N_NODES * 4);
    float* dinv     = (float*)alloc((size_t)N_NODES * 4);
    int*   row_ptr  = (int*)alloc((size_t)(N_NODES + 1) * 4);
    int*   cursor   = (int*)alloc((size_t)N_NODES * 4);
    uint2* csr      = (uint2*)alloc((size_t)N_EDGES * 8);
    int*   excl     = (int*)alloc((size_t)N_NODES * 4);
    int*   partials = (int*)alloc(256 * 4);
    int*   goff     = (int*)alloc((size_t)(G_NUM + 1) * 4);
    u16*   xb    = (u16*)alloc((size_t)N_NODES * F_IN_D * 2);  // 12.8 MB
    u16*   Xa    = (u16*)alloc((size_t)N_NODES * F_IN_D * 2);  // 12.8 MB
    u16*   H1    = (u16*)alloc((size_t)N_NODES * H_DIM * 2);   // 25.6 MB
    u16*   Ha    = (u16*)alloc((size_t)N_NODES * H_DIM * 2);   // 25.6 MB
    u16*   w1swz = (u16*)alloc((size_t)2 * F_IN_D * H_DIM * 2);
    u16*   w2swz = (u16*)alloc((size_t)2 * H_DIM * H_DIM * 2);
    float* pooled = (float*)alloc((size_t)G_NUM * H_DIM * 4);
    (void)ws_size; (void)n_in; (void)in_sizes; (void)out_size;

    const int NB_SCAN = (N_NODES + 255) / 256;   // 196
    const int GEMM_NB = (N_NODES + 63) / 64;     // 782

    hipMemsetAsync(hist, 0, (size_t)N_NODES * 4, stream);
    hipMemsetAsync(pooled, 0, (size_t)G_NUM * H_DIM * 4, stream);
    count_kernel<<<(N_EDGES + 255) / 256, 256, 0, stream>>>(dst, hist);
    bounds_kernel<<<NB_SCAN, 256, 0, stream>>>(batch, goff);
    scan_chunk_kernel<<<NB_SCAN, 256, 0, stream>>>(hist, excl, partials, dinv, N_NODES);
    scan_part_kernel <<<1, 256, 0, stream>>>(partials, NB_SCAN, row_ptr + N_NODES);
    scan_final_kernel<<<NB_SCAN, 256, 0, stream>>>(excl, partials, row_ptr, cursor, N_NODES);
    place_kernel<<<(N_EDGES + 255) / 256, 256, 0, stream>>>(src, dst, dinv, cursor, csr);
    conv_kernel <<<(NXQ + NW1 + NW2 + 255) / 256, 256, 0, stream>>>(x, xb, W1, w1swz, W2, w2swz);

    // layer 1: aggregate(x) then GEMM  (A_hat (X W) == (A_hat X) W)
    agg128_kernel<<<(N_NODES + 3) / 4, 256, 0, stream>>>(xb, dinv, row_ptr, csr, Xa);
    gemm1_kernel<F_IN_D><<<GEMM_NB, 256, 0, stream>>>(Xa, (const short8*)w1swz, b1, H1, N_NODES);
    // layer 2: aggregate(H1) then GEMM with fused mean-pool
    agg256_kernel<<<(N_NODES + 3) / 4, 256, 0, stream>>>(H1, dinv, row_ptr, csr, Ha);
    gemm2_pool_kernel<<<GEMM_NB, 256, 0, stream>>>(Ha, (const short8*)w2swz, b2, batch, pooled, N_NODES);

    head_kernel<<<G_NUM, 64, 0, stream>>>(pooled, goff, Wmu, bmu, Wlv, blv, (float*)d_out);
}

// Round 8
// 339.911 us; speedup vs baseline: 1.3553x; 1.0124x over previous
//
#include <hip/hip_runtime.h>

// Problem constants (from the reference file)
#define N_NODES 50000
#define N_EDGES 800000
#define F_IN_D  128
#define H_DIM   256
#define L_DIM   64
#define G_NUM   500

typedef unsigned int   u32;
typedef unsigned short u16;
typedef __attribute__((ext_vector_type(8))) short short8;
typedef __attribute__((ext_vector_type(4))) float f32x4;

static __device__ __forceinline__ float bf2f(u16 u) {
    union { u32 i; float f; } x; x.i = ((u32)u) << 16; return x.f;
}
static __device__ __forceinline__ u16 f2bf(float f) {
    union { float f; u32 i; } x; x.f = f;
    u32 r = (x.i + 0x7fffu + ((x.i >> 16) & 1u)) >> 16;
    return (u16)r;
}

// B-swizzle address (in u16 units): fragment layout for mfma_16x16x32_bf16.
static __device__ __forceinline__ u32 bswz_idx(int n, int k, int plane, int KS) {
    int n0g = n >> 6, nt = (n >> 4) & 3, lr = n & 15;
    int k0i = k >> 5, ks = k & 31, lq = ks >> 3, j = ks & 7;
    return ((u32)((((n0g * KS + k0i) * 2 + plane) * 4 + nt) * 64 + lq * 16 + lr)) * 8 + j;
}

// ---------------------------------------------------------------------------
// Fused preprocessing: degree count + batch bounds + all dtype conversions.
// Independent jobs mapped onto disjoint blockIdx ranges of one dispatch —
// overlaps atomic-bound (count) with copy-bound (conv) work, saves 2 launches.
// ---------------------------------------------------------------------------
#define NXQ (N_NODES * F_IN_D / 4)          // 1,600,000
#define NW1 (F_IN_D * H_DIM)                // 32,768
#define NW2 (H_DIM * H_DIM)                 // 65,536
#define NB_COUNT ((N_EDGES + 255) / 256)            // 3125
#define NB_SCAN  ((N_NODES + 255) / 256)            // 196
#define NB_CONV  ((NXQ + NW1 + NW2 + 255) / 256)    // 6634

__global__ void prep_kernel(const int* __restrict__ dst, int* __restrict__ hist,
                            const int* __restrict__ batch, int* __restrict__ goff,
                            const float* __restrict__ x, u16* __restrict__ xb,
                            const float* __restrict__ W1, u16* __restrict__ w1swz,
                            const float* __restrict__ W2, u16* __restrict__ w2swz) {
    int b = blockIdx.x;
    if (b < NB_COUNT) {
        // degree histogram — random-address atomics parallelize across channels
        int i = b * 256 + threadIdx.x;
        if (i < N_EDGES) atomicAdd(&hist[dst[i]], 1);
    } else if (b < NB_COUNT + NB_SCAN) {
        // batch sorted: graph start offsets via boundary detection, no atomics
        int i = (b - NB_COUNT) * 256 + threadIdx.x;
        if (i >= N_NODES) return;
        int v = batch[i];
        if (i == 0) {
            for (int g = 0; g <= v; ++g) goff[g] = 0;
        } else {
            int p = batch[i - 1];
            for (int g = p + 1; g <= v; ++g) goff[g] = i;
        }
        if (i == N_NODES - 1) {
            for (int g = v + 1; g <= G_NUM; ++g) goff[g] = N_NODES;
        }
    } else {
        int i = (b - NB_COUNT - NB_SCAN) * 256 + threadIdx.x;
        if (i < NXQ) {
            float4 v = *(const float4*)&x[(size_t)i * 4];
            ushort4 o;
            o.x = f2bf(v.x); o.y = f2bf(v.y); o.z = f2bf(v.z); o.w = f2bf(v.w);
            *(ushort4*)&xb[(size_t)i * 4] = o;
        } else if (i < NXQ + NW1) {
            int idx = i - NXQ;
            int k = idx >> 8, n = idx & 255;
            float w = W1[idx];
            u16 h = f2bf(w);
            w1swz[bswz_idx(n, k, 0, F_IN_D / 32)] = h;
            w1swz[bswz_idx(n, k, 1, F_IN_D / 32)] = f2bf(w - bf2f(h));
        } else if (i < NXQ + NW1 + NW2) {
            int idx = i - NXQ - NW1;
            int k = idx >> 8, n = idx & 255;
            float w = W2[idx];
            u16 h = f2bf(w);
            w2swz[bswz_idx(n, k, 0, H_DIM / 32)] = h;
            w2swz[bswz_idx(n, k, 1, H_DIM / 32)] = f2bf(w - bf2f(h));
        }
    }
}

// exclusive scan of hist (chunk=256) + fused dinv computation
__global__ void scan_chunk_kernel(const int* __restrict__ in, int* __restrict__ excl,
                                  int* __restrict__ partials, float* __restrict__ dinv, int n) {
    __shared__ int sm[256];
    int t = threadIdx.x;
    int i = blockIdx.x * 256 + t;
    int v = (i < n) ? in[i] : 0;
    sm[t] = v; __syncthreads();
    for (int off = 1; off < 256; off <<= 1) {
        int x = (t >= off) ? sm[t - off] : 0;
        __syncthreads();
        sm[t] += x;
        __syncthreads();
    }
    if (i < n) {
        excl[i] = sm[t] - v;
        dinv[i] = 1.0f / sqrtf((float)(v + 1));   // +1 self loop
    }
    if (t == 255) partials[blockIdx.x] = sm[255];
}

// final: each block redundantly scans the raw partials (196 <= 256) in LDS —
// removes the 1-block scan_part kernel (pure serialization) entirely.
__global__ void scan_final_kernel(const int* __restrict__ excl, const int* __restrict__ partials,
                                  int* __restrict__ out, int* __restrict__ cursor, int n, int nb) {
    __shared__ int sm[256];
    int t = threadIdx.x;
    int v = (t < nb) ? partials[t] : 0;
    sm[t] = v; __syncthreads();
    for (int off = 1; off < 256; off <<= 1) {
        int x = (t >= off) ? sm[t - off] : 0;
        __syncthreads();
        sm[t] += x;
        __syncthreads();
    }
    int pre = (blockIdx.x > 0) ? sm[blockIdx.x - 1] : 0;   // uniform read
    int i = blockIdx.x * 256 + t;
    if (i < n) {
        int val = excl[i] + pre;
        out[i] = val;
        cursor[i] = val;
    }
    if (blockIdx.x == (unsigned)(nb - 1) && t == 0) out[n] = sm[nb - 1];
}

// CSR entries packed (src, bits(dinv[src]))
__global__ void place_kernel(const int* __restrict__ src, const int* __restrict__ dst,
                             const float* __restrict__ dinv,
                             int* __restrict__ cursor, uint2* __restrict__ csr) {
    int e = blockIdx.x * 256 + threadIdx.x;
    if (e < N_EDGES) {
        int s = src[e];
        int d = dst[e];
        int pos = atomicAdd(&cursor[d], 1);
        csr[pos] = make_uint2((u32)s, __float_as_uint(dinv[s]));
    }
}

// ---------------------------------------------------------------------------
// GCN aggregation, bf16 in -> bf16 out. One wave per node, edge loop x8/x4.
// At the vector-load-path roofline (~11 B/cyc/CU request throughput, r7).
// ---------------------------------------------------------------------------
__global__ __launch_bounds__(256)
void agg128_kernel(const u16* __restrict__ In, const float* __restrict__ dinv,
                   const int* __restrict__ rp, const uint2* __restrict__ csr,
                   u16* __restrict__ Out) {
    int node = blockIdx.x * 4 + (threadIdx.x >> 6);
    int lane = threadIdx.x & 63;
    if (node >= N_NODES) return;
    int c = lane * 2;
    float di = dinv[node];
    int r0 = rp[node], r1 = rp[node + 1];
    u32 sv = *(const u32*)&In[(size_t)node * 128 + c];
    float a0 = di * bf2f((u16)(sv & 0xffff));
    float a1 = di * bf2f((u16)(sv >> 16));
    int j = r0;
    for (; j + 8 <= r1; j += 8) {
        uint2 e[8];
        u32 v[8];
#pragma unroll
        for (int q = 0; q < 8; ++q) e[q] = csr[j + q];
#pragma unroll
        for (int q = 0; q < 8; ++q) v[q] = *(const u32*)&In[(size_t)e[q].x * 128 + c];
#pragma unroll
        for (int q = 0; q < 8; ++q) {
            float w = __uint_as_float(e[q].y);
            a0 = fmaf(w, bf2f((u16)(v[q] & 0xffff)), a0);
            a1 = fmaf(w, bf2f((u16)(v[q] >> 16)), a1);
        }
    }
    for (; j + 4 <= r1; j += 4) {
        uint2 e[4];
        u32 v[4];
#pragma unroll
        for (int q = 0; q < 4; ++q) e[q] = csr[j + q];
#pragma unroll
        for (int q = 0; q < 4; ++q) v[q] = *(const u32*)&In[(size_t)e[q].x * 128 + c];
#pragma unroll
        for (int q = 0; q < 4; ++q) {
            float w = __uint_as_float(e[q].y);
            a0 = fmaf(w, bf2f((u16)(v[q] & 0xffff)), a0);
            a1 = fmaf(w, bf2f((u16)(v[q] >> 16)), a1);
        }
    }
    for (; j < r1; ++j) {
        uint2 e = csr[j];
        u32 v = *(const u32*)&In[(size_t)e.x * 128 + c];
        float w = __uint_as_float(e.y);
        a0 = fmaf(w, bf2f((u16)(v & 0xffff)), a0);
        a1 = fmaf(w, bf2f((u16)(v >> 16)), a1);
    }
    u32 o = ((u32)f2bf(di * a1) << 16) | (u32)f2bf(di * a0);
    *(u32*)&Out[(size_t)node * 128 + c] = o;
}

__global__ __launch_bounds__(256)
void agg256_kernel(const u16* __restrict__ In, const float* __restrict__ dinv,
                   const int* __restrict__ rp, const uint2* __restrict__ csr,
                   u16* __restrict__ Out) {
    int node = blockIdx.x * 4 + (threadIdx.x >> 6);
    int lane = threadIdx.x & 63;
    if (node >= N_NODES) return;
    int c = lane * 4;
    float di = dinv[node];
    int r0 = rp[node], r1 = rp[node + 1];
    uint2 sv = *(const uint2*)&In[(size_t)node * 256 + c];
    float a0 = di * bf2f((u16)(sv.x & 0xffff));
    float a1 = di * bf2f((u16)(sv.x >> 16));
    float a2 = di * bf2f((u16)(sv.y & 0xffff));
    float a3 = di * bf2f((u16)(sv.y >> 16));
    int j = r0;
    for (; j + 8 <= r1; j += 8) {
        uint2 e[8];
        uint2 v[8];
#pragma unroll
        for (int q = 0; q < 8; ++q) e[q] = csr[j + q];
#pragma unroll
        for (int q = 0; q < 8; ++q) v[q] = *(const uint2*)&In[(size_t)e[q].x * 256 + c];
#pragma unroll
        for (int q = 0; q < 8; ++q) {
            float w = __uint_as_float(e[q].y);
            a0 = fmaf(w, bf2f((u16)(v[q].x & 0xffff)), a0);
            a1 = fmaf(w, bf2f((u16)(v[q].x >> 16)), a1);
            a2 = fmaf(w, bf2f((u16)(v[q].y & 0xffff)), a2);
            a3 = fmaf(w, bf2f((u16)(v[q].y >> 16)), a3);
        }
    }
    for (; j + 4 <= r1; j += 4) {
        uint2 e[4];
        uint2 v[4];
#pragma unroll
        for (int q = 0; q < 4; ++q) e[q] = csr[j + q];
#pragma unroll
        for (int q = 0; q < 4; ++q) v[q] = *(const uint2*)&In[(size_t)e[q].x * 256 + c];
#pragma unroll
        for (int q = 0; q < 4; ++q) {
            float w = __uint_as_float(e[q].y);
            a0 = fmaf(w, bf2f((u16)(v[q].x & 0xffff)), a0);
            a1 = fmaf(w, bf2f((u16)(v[q].x >> 16)), a1);
            a2 = fmaf(w, bf2f((u16)(v[q].y & 0xffff)), a2);
            a3 = fmaf(w, bf2f((u16)(v[q].y >> 16)), a3);
        }
    }
    for (; j < r1; ++j) {
        uint2 e = csr[j];
        uint2 v = *(const uint2*)&In[(size_t)e.x * 256 + c];
        float w = __uint_as_float(e.y);
        a0 = fmaf(w, bf2f((u16)(v.x & 0xffff)), a0);
        a1 = fmaf(w, bf2f((u16)(v.x >> 16)), a1);
        a2 = fmaf(w, bf2f((u16)(v.y & 0xffff)), a2);
        a3 = fmaf(w, bf2f((u16)(v.y >> 16)), a3);
    }
    uint2 o;
    o.x = ((u32)f2bf(di * a1) << 16) | (u32)f2bf(di * a0);
    o.y = ((u32)f2bf(di * a3) << 16) | (u32)f2bf(di * a2);
    *(uint2*)&Out[(size_t)node * 256 + c] = o;
}

// ---------------------------------------------------------------------------
// MFMA GEMM layer 1: H1[M,256] = relu( A[M,128] @ W1 + b1 ), bf16 out.
// ---------------------------------------------------------------------------
template<int K>
__global__ __launch_bounds__(256, 3)
void gemm1_kernel(const u16* __restrict__ A, const short8* __restrict__ Bswz,
                  const float* __restrict__ bias, u16* __restrict__ Out, int M) {
    const int KS = K / 32;
    __shared__ u16 cst[64][264];
    int tid  = threadIdx.x;
    int wave = tid >> 6, lane = tid & 63;
    int m0 = blockIdx.x * 64;
    int n0 = wave * 64;
    int lr = lane & 15;
    int lk = (lane >> 4) * 8;

    f32x4 acc[4][4];
#pragma unroll
    for (int i = 0; i < 4; ++i)
#pragma unroll
        for (int j = 0; j < 4; ++j) acc[i][j] = {0.f, 0.f, 0.f, 0.f};

    for (int k0i = 0; k0i < KS; ++k0i) {
        int k0 = k0i * 32;
        short8 a[4], bh[4], bl[4];
#pragma unroll
        for (int mt = 0; mt < 4; ++mt) {
            int m = m0 + mt * 16 + lr;
            if (m > M - 1) m = M - 1;
            a[mt] = *(const short8*)&A[(size_t)m * K + k0 + lk];
        }
        const short8* bp = Bswz + ((size_t)(wave * KS + k0i) * 8) * 64 + lane;
#pragma unroll
        for (int nt = 0; nt < 4; ++nt) {
            bh[nt] = bp[(size_t)nt * 64];
            bl[nt] = bp[(size_t)(4 + nt) * 64];
        }
#pragma unroll
        for (int mt = 0; mt < 4; ++mt)
#pragma unroll
            for (int nt = 0; nt < 4; ++nt) {
                acc[mt][nt] = __builtin_amdgcn_mfma_f32_16x16x32_bf16(a[mt], bh[nt], acc[mt][nt], 0, 0, 0);
                acc[mt][nt] = __builtin_amdgcn_mfma_f32_16x16x32_bf16(a[mt], bl[nt], acc[mt][nt], 0, 0, 0);
            }
    }

#pragma unroll
    for (int mt = 0; mt < 4; ++mt)
#pragma unroll
        for (int nt = 0; nt < 4; ++nt) {
            int col = n0 + nt * 16 + lr;
            float b = bias[col];
#pragma unroll
            for (int r = 0; r < 4; ++r) {
                int row = mt * 16 + (lane >> 4) * 4 + r;
                cst[row][col] = f2bf(fmaxf(acc[mt][nt][r] + b, 0.f));
            }
        }
    __syncthreads();
#pragma unroll
    for (int p = 0; p < 8; ++p) {
        int row = p * 8 + (tid >> 5);
        int c16 = (tid & 31) * 8;
        int m = m0 + row;
        if (m < M) {
            uint4 v = *(const uint4*)&cst[row][c16];
            *(uint4*)&Out[(size_t)m * 256 + c16] = v;
        }
    }
}

// ---------------------------------------------------------------------------
// MFMA GEMM layer 2 + fused mean-pool
// ---------------------------------------------------------------------------
__global__ __launch_bounds__(256, 3)
void gemm2_pool_kernel(const u16* __restrict__ A, const short8* __restrict__ Bswz,
                       const float* __restrict__ bias, const int* __restrict__ batch,
                       float* __restrict__ pooled, int M) {
    const int K = H_DIM, KS = K / 32;
    __shared__ u16 cst[64][264];
    __shared__ int batch_s[64];
    int tid  = threadIdx.x;
    int wave = tid >> 6, lane = tid & 63;
    int m0 = blockIdx.x * 64;
    int n0 = wave * 64;
    int lr = lane & 15;
    int lk = (lane >> 4) * 8;

    f32x4 acc[4][4];
#pragma unroll
    for (int i = 0; i < 4; ++i)
#pragma unroll
        for (int j = 0; j < 4; ++j) acc[i][j] = {0.f, 0.f, 0.f, 0.f};

    for (int k0i = 0; k0i < KS; ++k0i) {
        int k0 = k0i * 32;
        short8 a[4], bh[4], bl[4];
#pragma unroll
        for (int mt = 0; mt < 4; ++mt) {
            int m = m0 + mt * 16 + lr;
            if (m > M - 1) m = M - 1;
            a[mt] = *(const short8*)&A[(size_t)m * K + k0 + lk];
        }
        const short8* bp = Bswz + ((size_t)(wave * KS + k0i) * 8) * 64 + lane;
#pragma unroll
        for (int nt = 0; nt < 4; ++nt) {
            bh[nt] = bp[(size_t)nt * 64];
            bl[nt] = bp[(size_t)(4 + nt) * 64];
        }
#pragma unroll
        for (int mt = 0; mt < 4; ++mt)
#pragma unroll
            for (int nt = 0; nt < 4; ++nt) {
                acc[mt][nt] = __builtin_amdgcn_mfma_f32_16x16x32_bf16(a[mt], bh[nt], acc[mt][nt], 0, 0, 0);
                acc[mt][nt] = __builtin_amdgcn_mfma_f32_16x16x32_bf16(a[mt], bl[nt], acc[mt][nt], 0, 0, 0);
            }
    }

    if (tid < 64) {
        int m = m0 + tid;
        batch_s[tid] = (m < M) ? batch[m] : -1;
    }
#pragma unroll
    for (int mt = 0; mt < 4; ++mt)
#pragma unroll
        for (int nt = 0; nt < 4; ++nt) {
            int col = n0 + nt * 16 + lr;
            float b = bias[col];
#pragma unroll
            for (int r = 0; r < 4; ++r) {
                int row = mt * 16 + (lane >> 4) * 4 + r;
                cst[row][col] = f2bf(fmaxf(acc[mt][nt][r] + b, 0.f));
            }
        }
    __syncthreads();

    // segmented pooling: thread = column, walk the 64 sorted rows
    int rows = M - m0; if (rows > 64) rows = 64;
    float s = 0.f;
    int gp = batch_s[0];
    for (int r = 0; r < rows; ++r) {
        int g = batch_s[r];
        if (g != gp) {
            atomicAdd(&pooled[(size_t)gp * H_DIM + tid], s);
            s = 0.f;
            gp = g;
        }
        s += bf2f(cst[r][tid]);
    }
    atomicAdd(&pooled[(size_t)gp * H_DIM + tid], s);
}

// ---------------------------------------------------------------------------
// Heads (fp32): h_graph = pooled/cnt (cnt from goff diffs); mu/logvar heads
// ---------------------------------------------------------------------------
__global__ void head_kernel(const float* __restrict__ pooled, const int* __restrict__ goff,
                            const float* __restrict__ Wmu, const float* __restrict__ bmu,
                            const float* __restrict__ Wlv, const float* __restrict__ blv,
                            float* __restrict__ out) {
    __shared__ float hg[H_DIM];
    int g = blockIdx.x, l = threadIdx.x;   // 64 threads
    float inv = 1.0f / fmaxf((float)(goff[g + 1] - goff[g]), 1.0f);
    for (int k = l; k < H_DIM; k += 64) hg[k] = pooled[(size_t)g * H_DIM + k] * inv;
    __syncthreads();
    float mu = bmu[l], lv = blv[l];
    for (int k = 0; k < H_DIM; ++k) {
        float h = hg[k];
        mu = fmaf(h, Wmu[k * L_DIM + l], mu);
        lv = fmaf(h, Wlv[k * L_DIM + l], lv);
    }
    out[(size_t)g * L_DIM + l] = mu;
    out[(size_t)G_NUM * L_DIM + (size_t)g * L_DIM + l] = lv;
}

// ---------------------------------------------------------------------------
extern "C" void kernel_launch(void* const* d_in, const int* in_sizes, int n_in,
                              void* d_out, int out_size, void* d_ws, size_t ws_size,
                              hipStream_t stream) {
    const float* x     = (const float*)d_in[0];
    const int*   ei    = (const int*)  d_in[1];
    const int*   batch = (const int*)  d_in[2];
    const float* W1  = (const float*)d_in[4];
    const float* b1  = (const float*)d_in[5];
    const float* W2  = (const float*)d_in[6];
    const float* b2  = (const float*)d_in[7];
    const float* Wmu = (const float*)d_in[8];
    const float* bmu = (const float*)d_in[9];
    const float* Wlv = (const float*)d_in[10];
    const float* blv = (const float*)d_in[11];
    const int* src = ei;
    const int* dst = ei + N_EDGES;

    char* ws = (char*)d_ws;
    size_t off = 0;
    auto alloc = [&](size_t bytes) -> void* {
        void* p = ws + off;
        off += (bytes + 255) & ~(size_t)255;
        return p;
    };
    // hist + pooled adjacent -> one memset clears both
    int*   hist     = (int*)alloc((size_t)N_NODES * 4);
    float* pooled   = (float*)alloc((size_t)G_NUM * H_DIM * 4);
    float* dinv     = (float*)alloc((size_t)N_NODES * 4);
    int*   row_ptr  = (int*)alloc((size_t)(N_NODES + 1) * 4);
    int*   cursor   = (int*)alloc((size_t)N_NODES * 4);
    uint2* csr      = (uint2*)alloc((size_t)N_EDGES * 8);
    int*   excl     = (int*)alloc((size_t)N_NODES * 4);
    int*   partials = (int*)alloc(256 * 4);
    int*   goff     = (int*)alloc((size_t)(G_NUM + 1) * 4);
    u16*   xb    = (u16*)alloc((size_t)N_NODES * F_IN_D * 2);  // 12.8 MB
    u16*   Xa    = (u16*)alloc((size_t)N_NODES * F_IN_D * 2);  // 12.8 MB
    u16*   H1    = (u16*)alloc((size_t)N_NODES * H_DIM * 2);   // 25.6 MB
    u16*   Ha    = (u16*)alloc((size_t)N_NODES * H_DIM * 2);   // 25.6 MB
    u16*   w1swz = (u16*)alloc((size_t)2 * F_IN_D * H_DIM * 2);
    u16*   w2swz = (u16*)alloc((size_t)2 * H_DIM * H_DIM * 2);
    (void)ws_size; (void)n_in; (void)in_sizes; (void)out_size;

    const int GEMM_NB = (N_NODES + 63) / 64;     // 782
    size_t zero_bytes = (size_t)((char*)(pooled + G_NUM * H_DIM) - (char*)hist);

    hipMemsetAsync(hist, 0, zero_bytes, stream);
    prep_kernel<<<NB_COUNT + NB_SCAN + NB_CONV, 256, 0, stream>>>(
        dst, hist, batch, goff, x, xb, W1, w1swz, W2, w2swz);
    scan_chunk_kernel<<<NB_SCAN, 256, 0, stream>>>(hist, excl, partials, dinv, N_NODES);
    scan_final_kernel<<<NB_SCAN, 256, 0, stream>>>(excl, partials, row_ptr, cursor, N_NODES, NB_SCAN);
    place_kernel<<<(N_EDGES + 255) / 256, 256, 0, stream>>>(src, dst, dinv, cursor, csr);

    // layer 1: aggregate(x) then GEMM  (A_hat (X W) == (A_hat X) W)
    agg128_kernel<<<(N_NODES + 3) / 4, 256, 0, stream>>>(xb, dinv, row_ptr, csr, Xa);
    gemm1_kernel<F_IN_D><<<GEMM_NB, 256, 0, stream>>>(Xa, (const short8*)w1swz, b1, H1, N_NODES);
    // layer 2: aggregate(H1) then GEMM with fused mean-pool
    agg256_kernel<<<(N_NODES + 3) / 4, 256, 0, stream>>>(H1, dinv, row_ptr, csr, Ha);
    gemm2_pool_kernel<<<GEMM_NB, 256, 0, stream>>>(Ha, (const short8*)w2swz, b2, batch, pooled, N_NODES);

    head_kernel<<<G_NUM, 64, 0, stream>>>(pooled, goff, Wmu, bmu, Wlv, blv, (float*)d_out);
}